// Round 1
// 142.276 us; speedup vs baseline: 1.0042x; 1.0042x over previous
//
#include <hip/hip_runtime.h>
#include <hip/hip_bf16.h>

// FixedChannelDP via Toeplitz-GEMM on bf16 MFMA 32x32x16.
// y[p,n] = sum_{k=0}^{512} h[k] x[p,n-k]  ('full' conv), out fp32 [2,NOUT,2].
//
// Dual-pol register tiling: block covers n in [N0, N0+4096) for BOTH pols;
// each of 4 waves owns one 32x32-tile strip (1024 outputs) and computes BOTH
// pols for that strip, sharing the h fragments => 8 MFMAs per K-step from
// 2 global h loads + 4 LDS x loads, 4 independent acc chains (64 acc VGPRs).
//
// Mapping (b in [0,34)):
//   D[r][c] += sum_k A_b[r][k] * B_b[k][c],  n = nw + 32r + c
//   A_b[r][k] = x[nw + 32r + k + 16 - 16b]        (8 contiguous -> ds_read_b128)
//   B_b[k][c] = h[16b + c - k - 16]  (0 if OOB)   -> tap covered exactly once
// h table (global ws): hh[tab][R][j] = h[R-24-j], tab: 0=hr, 1=hi;
//   row read at R = 16b + cc - 8*half + 8.  re-part uses (-xi)*hi via v_xor.

#define NSAMP 4194304
#define LTAPS 513
#define NOUT  (NSAMP + LTAPS - 1)   // 4194816

#define BLK       256
#define WAVE_OUT  1024                  // one 32x32 D tile strip per wave
#define BLOCK_OUT 4096                  // per pol (4 strips x 4 waves)
#define HALO      512
#define XELEMS    (BLOCK_OUT + HALO + 16)   // 4624
#define NB        34
#define HROWS     568
#define NBLK      ((NOUT + BLOCK_OUT - 1) / BLOCK_OUT)  // 1025

typedef __attribute__((ext_vector_type(8)))  short short8;
typedef __attribute__((ext_vector_type(4)))  short short4v;
typedef __attribute__((ext_vector_type(4)))  int   int4v;
typedef __attribute__((ext_vector_type(16))) float float16v;

// x LDS swizzle: +8 elements (16 B) per 32 -> A-frag b128 reads hit all 32 banks.
__device__ __forceinline__ int xswz(int e) { return e + ((e >> 5) << 3); }
#define XSZ 5776   // xswz(4620)+4 = 5776 (8-short / 16B aligned)

__device__ __forceinline__ short f2b(float f) {
    __bf16 b = (__bf16)f;
    return __builtin_bit_cast(short, b);
}

__global__ __launch_bounds__(BLK)
void build_h(const float* __restrict__ hr, const float* __restrict__ hi,
             short* __restrict__ hh) {
    int R = blockIdx.x * BLK + threadIdx.x;
    if (R < HROWS) {
        short8 vr, vi;
        #pragma unroll
        for (int j = 0; j < 8; ++j) {
            int idx = R - 24 - j;
            bool ok = (idx >= 0) && (idx < LTAPS);
            vr[j] = f2b(ok ? hr[idx] : 0.0f);
            vi[j] = f2b(ok ? hi[idx] : 0.0f);
        }
        *(short8*)(hh + (size_t)(0 * HROWS + R) * 8) = vr;
        *(short8*)(hh + (size_t)(1 * HROWS + R) * 8) = vi;
    }
}

#define MFMA32(A, B, C) __builtin_amdgcn_mfma_f32_32x32x16_bf16((A), (B), (C), 0, 0, 0)

__device__ __forceinline__ short8 bneg8(short8 v) {
    int4v t = __builtin_bit_cast(int4v, v);
    t ^= (int4v){(int)0x80008000, (int)0x80008000, (int)0x80008000, (int)0x80008000};
    return __builtin_bit_cast(short8, t);
}

__global__ __launch_bounds__(BLK, 3)
void fir_mfma32w(const float* __restrict__ txr_all, const float* __restrict__ txi_all,
                 const short* __restrict__ hh, float2* __restrict__ out) {
    const int N0  = blockIdx.x * BLOCK_OUT;
    const int tid = threadIdx.x;

    __shared__ __align__(16) short xr_s[2][XSZ];
    __shared__ __align__(16) short xi_s[2][XSZ];

    // ---- stage x tiles (both pols) [N0-HALO, N0+BLOCK_OUT+16) as bf16, swizzled ----
    #pragma unroll
    for (int p = 0; p < 2; ++p) {
        const float* __restrict__ xr_g = txr_all + (size_t)p * NSAMP;
        const float* __restrict__ xi_g = txi_all + (size_t)p * NSAMP;
        #pragma unroll
        for (int it = 0; it < 5; ++it) {
            int e = (tid + it * BLK) * 4;
            if (e < XELEMS) {
                int g = N0 - HALO + e;
                float r0, r1, r2, r3, i0, i1, i2, i3;
                if (g >= 0 && g + 3 < NSAMP) {
                    float4 fr = *(const float4*)(xr_g + g);
                    float4 fi = *(const float4*)(xi_g + g);
                    r0 = fr.x; r1 = fr.y; r2 = fr.z; r3 = fr.w;
                    i0 = fi.x; i1 = fi.y; i2 = fi.z; i3 = fi.w;
                } else {
                    int gc0 = min(max(g + 0, 0), NSAMP - 1);
                    int gc1 = min(max(g + 1, 0), NSAMP - 1);
                    int gc2 = min(max(g + 2, 0), NSAMP - 1);
                    int gc3 = min(max(g + 3, 0), NSAMP - 1);
                    r0 = (g + 0 >= 0 && g + 0 < NSAMP) ? xr_g[gc0] : 0.0f;
                    r1 = (g + 1 >= 0 && g + 1 < NSAMP) ? xr_g[gc1] : 0.0f;
                    r2 = (g + 2 >= 0 && g + 2 < NSAMP) ? xr_g[gc2] : 0.0f;
                    r3 = (g + 3 >= 0 && g + 3 < NSAMP) ? xr_g[gc3] : 0.0f;
                    i0 = (g + 0 >= 0 && g + 0 < NSAMP) ? xi_g[gc0] : 0.0f;
                    i1 = (g + 1 >= 0 && g + 1 < NSAMP) ? xi_g[gc1] : 0.0f;
                    i2 = (g + 2 >= 0 && g + 2 < NSAMP) ? xi_g[gc2] : 0.0f;
                    i3 = (g + 3 >= 0 && g + 3 < NSAMP) ? xi_g[gc3] : 0.0f;
                }
                int ls = xswz(e);   // 4-aligned, never crosses a pad boundary
                short4v vr = { f2b(r0), f2b(r1), f2b(r2), f2b(r3) };
                short4v vi = { f2b(i0), f2b(i1), f2b(i2), f2b(i3) };
                *(short4v*)(&xr_s[p][ls]) = vr;
                *(short4v*)(&xi_s[p][ls]) = vi;
            }
        }
    }
    __syncthreads();

    // ---- MFMA main loop: one strip per wave, BOTH pols per wave (shared h) ----
    const int lane  = tid & 63;
    const int wave  = tid >> 6;
    const int strip = wave;         // 4 strips of 1024 outputs
    const int cc    = lane & 31;    // A row r / B col c / D col
    const int half  = lane >> 5;

    float16v zero = {0.f,0.f,0.f,0.f,0.f,0.f,0.f,0.f,0.f,0.f,0.f,0.f,0.f,0.f,0.f,0.f};
    float16v acc_re0 = zero, acc_im0 = zero, acc_re1 = zero, acc_im1 = zero;

    const int    ebase = HALO + strip * WAVE_OUT + 32 * cc + 8 * half + 16;
    const short* hp0   = hh + (size_t)(cc - 8 * half + 8) * 8;
    const short* xr0p  = xr_s[0];
    const short* xi0p  = xi_s[0];
    const short* xr1p  = xr_s[1];
    const short* xi1p  = xi_s[1];

    for (int b = 0; b < NB; ++b) {
        const short* hp = hp0 + (size_t)(16 * b) * 8;
        short8 fhr = *(const short8*)(hp);
        short8 fhi = *(const short8*)(hp + (size_t)HROWS * 8);
        int ls = xswz(ebase - 16 * b);
        short8 fxr0 = *(const short8*)(xr0p + ls);
        short8 fxi0 = *(const short8*)(xi0p + ls);
        short8 fxr1 = *(const short8*)(xr1p + ls);
        short8 fxi1 = *(const short8*)(xi1p + ls);
        short8 fnxi0 = bneg8(fxi0);
        short8 fnxi1 = bneg8(fxi1);
        // round 1: 4 independent chains on fhr
        acc_re0 = MFMA32(fxr0,  fhr, acc_re0);
        acc_im0 = MFMA32(fxi0,  fhr, acc_im0);
        acc_re1 = MFMA32(fxr1,  fhr, acc_re1);
        acc_im1 = MFMA32(fxi1,  fhr, acc_im1);
        // round 2: 4 independent chains on fhi
        acc_re0 = MFMA32(fnxi0, fhi, acc_re0);
        acc_im0 = MFMA32(fxr0,  fhi, acc_im0);
        acc_re1 = MFMA32(fnxi1, fhi, acc_re1);
        acc_im1 = MFMA32(fxr1,  fhi, acc_im1);
    }

    // ---- epilogue: D col = lane&31, row = (reg&3) + 8*(reg>>2) + 4*half ----
    float2* __restrict__ op0 = out;
    float2* __restrict__ op1 = out + (size_t)NOUT;
    const int nw = N0 + strip * WAVE_OUT;
    #pragma unroll
    for (int v = 0; v < 16; ++v) {
        int row = (v & 3) + 8 * (v >> 2) + 4 * half;
        int n = nw + 32 * row + cc;
        if (n < NOUT) {
            op0[n] = make_float2(acc_re0[v], acc_im0[v]);
            op1[n] = make_float2(acc_re1[v], acc_im1[v]);
        }
    }
}

extern "C" void kernel_launch(void* const* d_in, const int* in_sizes, int n_in,
                              void* d_out, int out_size, void* d_ws, size_t ws_size,
                              hipStream_t stream) {
    const float* txr = (const float*)d_in[0];
    const float* txi = (const float*)d_in[1];
    const float* hr  = (const float*)d_in[2];
    const float* hi  = (const float*)d_in[3];
    float2* out = (float2*)d_out;
    short* hh = (short*)d_ws;   // 2 * 568 * 8 bf16 = 18 KB

    build_h<<<dim3((HROWS + BLK - 1) / BLK), BLK, 0, stream>>>(hr, hi, hh);

    fir_mfma32w<<<dim3(NBLK), BLK, 0, stream>>>(txr, txi, hh, out);
}

// Round 2
// 140.667 us; speedup vs baseline: 1.0156x; 1.0114x over previous
//
#include <hip/hip_runtime.h>
#include <hip/hip_bf16.h>

// FixedChannelDP via Toeplitz-GEMM on bf16 MFMA 32x32x16.
// y[p,n] = sum_{k=0}^{512} h[k] x[p,n-k]  ('full' conv), out fp32 [2,NOUT,2].
//
// Dual-pol register tiling + software-pipelined K-loop:
//   - each of 4 waves owns one 32x32-tile strip (1024 outputs) and computes
//     BOTH pols (shared h frags): 8 MFMAs / K-step, 4 independent acc chains.
//   - K-loop register double-buffer: iteration b prefetches b+1's 4 LDS x-frags
//     + 2 global h-frags BEFORE issuing b's 8 MFMAs (256 SIMD-cyc of cover).
//   - zero-space XOR LDS swizzle (e ^= ((e>>6)&7)<<3) instead of +25% pad:
//     LDS 46.6 -> 36.1 KB => 4 blocks/CU (16 waves).
//
// Mapping (b in [0,34)):
//   D[r][c] += sum_k A_b[r][k] * B_b[k][c],  n = nw + 32r + c
//   A_b[r][k] = x[nw + 32r + k + 16 - 16b]        (8 contiguous -> ds_read_b128)
//   B_b[k][c] = h[16b + c - k - 16]  (0 if OOB)   -> tap covered exactly once
// h table (global ws): hh[tab][R][j] = h[R-24-j], tab: 0=hr, 1=hi;
//   row read at R = 16b + cc - 8*half + 8; rows >= 544 are all-zero (prefetch-safe).
//   re-part uses xi*(-hi) via one v_xor on the h fragment.

#define NSAMP 4194304
#define LTAPS 513
#define NOUT  (NSAMP + LTAPS - 1)   // 4194816

#define BLK       256
#define WAVE_OUT  1024                  // one 32x32 D tile strip per wave
#define BLOCK_OUT 4096                  // per pol (4 strips x 4 waves)
#define HALO      512
#define XELEMS    (BLOCK_OUT + HALO + 16)   // 4624
#define NB        34
#define HROWS     592                   // >= 584 so b=NB prefetch stays in-bounds (zero rows)
#define NBLK      ((NOUT + BLOCK_OUT - 1) / BLOCK_OUT)  // 1025

typedef __attribute__((ext_vector_type(8)))  short short8;
typedef __attribute__((ext_vector_type(4)))  short short4v;
typedef __attribute__((ext_vector_type(4)))  int   int4v;
typedef __attribute__((ext_vector_type(16))) float float16v;

// XOR swizzle, zero space overhead: folds element bits [6:8] into bits [3:5].
// Bijective within each 64-elem block; preserves 8-elem (16 B) alignment, so
// b128 reads and 4-elem (8 B) staged writes move as units.  A-frag reads at
// 64 B/lane stride spread over ~8 bank-groups instead of 2.
__device__ __forceinline__ int xswz(int e) { return e ^ (((e >> 6) & 7) << 3); }
#define XSZ 4624   // XOR stays within 64-elem blocks => no extra space

__device__ __forceinline__ short f2b(float f) {
    __bf16 b = (__bf16)f;
    return __builtin_bit_cast(short, b);
}

__global__ __launch_bounds__(BLK)
void build_h(const float* __restrict__ hr, const float* __restrict__ hi,
             short* __restrict__ hh) {
    int R = blockIdx.x * BLK + threadIdx.x;
    if (R < HROWS) {
        short8 vr, vi;
        #pragma unroll
        for (int j = 0; j < 8; ++j) {
            int idx = R - 24 - j;
            bool ok = (idx >= 0) && (idx < LTAPS);
            vr[j] = f2b(ok ? hr[idx] : 0.0f);
            vi[j] = f2b(ok ? hi[idx] : 0.0f);
        }
        *(short8*)(hh + (size_t)(0 * HROWS + R) * 8) = vr;
        *(short8*)(hh + (size_t)(1 * HROWS + R) * 8) = vi;
    }
}

#define MFMA32(A, B, C) __builtin_amdgcn_mfma_f32_32x32x16_bf16((A), (B), (C), 0, 0, 0)

__device__ __forceinline__ short8 bneg8(short8 v) {
    int4v t = __builtin_bit_cast(int4v, v);
    t ^= (int4v){(int)0x80008000, (int)0x80008000, (int)0x80008000, (int)0x80008000};
    return __builtin_bit_cast(short8, t);
}

__global__ __launch_bounds__(BLK, 4)
void fir_mfma32w(const float* __restrict__ txr_all, const float* __restrict__ txi_all,
                 const short* __restrict__ hh, float2* __restrict__ out) {
    const int N0  = blockIdx.x * BLOCK_OUT;
    const int tid = threadIdx.x;

    // [0]=xr pol0, [1]=xi pol0, [2]=xr pol1, [3]=xi pol1 — contiguous so the
    // 4 fragment reads share one address register + immediate ds offsets.
    __shared__ __align__(16) short xs[4][XSZ];

    // ---- stage x tiles (both pols) [N0-HALO, N0+BLOCK_OUT+16) as bf16, swizzled ----
    #pragma unroll
    for (int p = 0; p < 2; ++p) {
        const float* __restrict__ xr_g = txr_all + (size_t)p * NSAMP;
        const float* __restrict__ xi_g = txi_all + (size_t)p * NSAMP;
        #pragma unroll
        for (int it = 0; it < 5; ++it) {
            int e = (tid + it * BLK) * 4;
            if (e < XELEMS) {
                int g = N0 - HALO + e;
                float r0, r1, r2, r3, i0, i1, i2, i3;
                if (g >= 0 && g + 3 < NSAMP) {
                    float4 fr = *(const float4*)(xr_g + g);
                    float4 fi = *(const float4*)(xi_g + g);
                    r0 = fr.x; r1 = fr.y; r2 = fr.z; r3 = fr.w;
                    i0 = fi.x; i1 = fi.y; i2 = fi.z; i3 = fi.w;
                } else {
                    int gc0 = min(max(g + 0, 0), NSAMP - 1);
                    int gc1 = min(max(g + 1, 0), NSAMP - 1);
                    int gc2 = min(max(g + 2, 0), NSAMP - 1);
                    int gc3 = min(max(g + 3, 0), NSAMP - 1);
                    r0 = (g + 0 >= 0 && g + 0 < NSAMP) ? xr_g[gc0] : 0.0f;
                    r1 = (g + 1 >= 0 && g + 1 < NSAMP) ? xr_g[gc1] : 0.0f;
                    r2 = (g + 2 >= 0 && g + 2 < NSAMP) ? xr_g[gc2] : 0.0f;
                    r3 = (g + 3 >= 0 && g + 3 < NSAMP) ? xr_g[gc3] : 0.0f;
                    i0 = (g + 0 >= 0 && g + 0 < NSAMP) ? xi_g[gc0] : 0.0f;
                    i1 = (g + 1 >= 0 && g + 1 < NSAMP) ? xi_g[gc1] : 0.0f;
                    i2 = (g + 2 >= 0 && g + 2 < NSAMP) ? xi_g[gc2] : 0.0f;
                    i3 = (g + 3 >= 0 && g + 3 < NSAMP) ? xi_g[gc3] : 0.0f;
                }
                int ls = xswz(e);   // 4-aligned within an 8-block: XOR constant
                short4v vr = { f2b(r0), f2b(r1), f2b(r2), f2b(r3) };
                short4v vi = { f2b(i0), f2b(i1), f2b(i2), f2b(i3) };
                *(short4v*)(&xs[2 * p + 0][ls]) = vr;
                *(short4v*)(&xs[2 * p + 1][ls]) = vi;
            }
        }
    }
    __syncthreads();

    // ---- MFMA main loop: one strip per wave, BOTH pols per wave (shared h) ----
    const int lane  = tid & 63;
    const int wave  = tid >> 6;
    const int strip = wave;         // 4 strips of 1024 outputs
    const int cc    = lane & 31;    // A row r / B col c / D col
    const int half  = lane >> 5;

    float16v zero = {0.f,0.f,0.f,0.f,0.f,0.f,0.f,0.f,0.f,0.f,0.f,0.f,0.f,0.f,0.f,0.f};
    float16v acc_re0 = zero, acc_im0 = zero, acc_re1 = zero, acc_im1 = zero;

    const int    ebase = HALO + strip * WAVE_OUT + 32 * cc + 8 * half + 16;
    const short* hpr   = hh + (size_t)(cc - 8 * half + 8) * 8;
    const short* xb    = &xs[0][0];

    // prologue: fragments for b=0
    int ls0 = xswz(ebase);
    short8 fxr0 = *(const short8*)(xb + ls0);
    short8 fxi0 = *(const short8*)(xb + XSZ + ls0);
    short8 fxr1 = *(const short8*)(xb + 2 * XSZ + ls0);
    short8 fxi1 = *(const short8*)(xb + 3 * XSZ + ls0);
    short8 fhr  = *(const short8*)(hpr);
    short8 fhi  = *(const short8*)(hpr + (size_t)HROWS * 8);

    #pragma unroll 2
    for (int b = 0; b < NB; ++b) {
        // ---- prefetch b+1 operands before b's MFMAs ----
        int en = ebase - 16 * (b + 1);
        en = en < 0 ? 0 : en;           // b=NB-1 prefetch: clamp into LDS (unused)
        int lsn = xswz(en);
        short8 nxr0 = *(const short8*)(xb + lsn);
        short8 nxi0 = *(const short8*)(xb + XSZ + lsn);
        short8 nxr1 = *(const short8*)(xb + 2 * XSZ + lsn);
        short8 nxi1 = *(const short8*)(xb + 3 * XSZ + lsn);
        const short* hn = hpr + (size_t)(16 * (b + 1)) * 8;
        short8 nhr = *(const short8*)(hn);
        short8 nhi = *(const short8*)(hn + (size_t)HROWS * 8);

        // ---- 8 MFMAs on current fragments (4 independent chains) ----
        short8 fnhi = bneg8(fhi);       // re-part: xi * (-hi)
        acc_re0 = MFMA32(fxr0, fhr,  acc_re0);
        acc_im0 = MFMA32(fxi0, fhr,  acc_im0);
        acc_re1 = MFMA32(fxr1, fhr,  acc_re1);
        acc_im1 = MFMA32(fxi1, fhr,  acc_im1);
        acc_re0 = MFMA32(fxi0, fnhi, acc_re0);
        acc_im0 = MFMA32(fxr0, fhi,  acc_im0);
        acc_re1 = MFMA32(fxi1, fnhi, acc_re1);
        acc_im1 = MFMA32(fxr1, fhi,  acc_im1);

        // rotate
        fxr0 = nxr0; fxi0 = nxi0; fxr1 = nxr1; fxi1 = nxi1;
        fhr  = nhr;  fhi  = nhi;
    }

    // ---- epilogue: D col = lane&31, row = (reg&3) + 8*(reg>>2) + 4*half ----
    float2* __restrict__ op0 = out;
    float2* __restrict__ op1 = out + (size_t)NOUT;
    const int nw = N0 + strip * WAVE_OUT;
    #pragma unroll
    for (int v = 0; v < 16; ++v) {
        int row = (v & 3) + 8 * (v >> 2) + 4 * half;
        int n = nw + 32 * row + cc;
        if (n < NOUT) {
            op0[n] = make_float2(acc_re0[v], acc_im0[v]);
            op1[n] = make_float2(acc_re1[v], acc_im1[v]);
        }
    }
}

extern "C" void kernel_launch(void* const* d_in, const int* in_sizes, int n_in,
                              void* d_out, int out_size, void* d_ws, size_t ws_size,
                              hipStream_t stream) {
    const float* txr = (const float*)d_in[0];
    const float* txi = (const float*)d_in[1];
    const float* hr  = (const float*)d_in[2];
    const float* hi  = (const float*)d_in[3];
    float2* out = (float2*)d_out;
    short* hh = (short*)d_ws;   // 2 * 592 * 8 bf16 ≈ 19 KB

    build_h<<<dim3((HROWS + BLK - 1) / BLK), BLK, 0, stream>>>(hr, hi, hh);

    fir_mfma32w<<<dim3(NBLK), BLK, 0, stream>>>(txr, txi, hh, out);
}